// Round 1
// baseline (128.196 us; speedup 1.0000x reference)
//
#include <hip/hip_runtime.h>
#include <math.h>

#define BB 64
#define TT 2048
#define DD 512
#define UU 10
#define S_CHUNKS 16
#define CHUNK_T (TT / S_CHUNKS)   // 128 t per block, 32 per wave

__device__ __forceinline__ float fast_tanh(float x) {
    // tanh(x) = 1 - 2/(1+e^{2x}); robust at +-inf (exp->inf => 1, exp->0 => -1)
    return 1.0f - 2.0f / (1.0f + __expf(2.0f * x));
}

// Pass 1: per (batch, T-chunk) block: scores + online-softmax partial context.
// wave <-> one t per iter; lane holds d-slice {4*lane+j, 256+4*lane+j}.
__global__ __launch_bounds__(256) void attn_pass1(
    const float* __restrict__ Eo, const float* __restrict__ H,
    const float* __restrict__ W_eo, const float* __restrict__ b_eo,
    const float* __restrict__ W_h, const float* __restrict__ b_h,
    const float* __restrict__ W_s, const float* __restrict__ b_s,
    float* __restrict__ scores, float* __restrict__ pm,
    float* __restrict__ pl, float* __restrict__ pc)
{
    const int b     = blockIdx.y;
    const int chunk = blockIdx.x;
    const int tid   = threadIdx.x;
    const int wave  = tid >> 6;
    const int lane  = tid & 63;

    // ---- hb[u] = (H[b]*W_h)[u] + b_h[u] + b_eo[u]  (each wave redundantly)
    float hacc[UU];
    #pragma unroll
    for (int u = 0; u < UU; ++u) hacc[u] = 0.f;
    const float* Hb = H + (size_t)b * DD;
    #pragma unroll
    for (int k = 0; k < DD / 64; ++k) {
        float hv = Hb[k * 64 + lane];
        const float* wr = W_h + (size_t)(k * 64 + lane) * UU;
        #pragma unroll
        for (int u = 0; u < UU; ++u) hacc[u] += hv * wr[u];
    }
    #pragma unroll
    for (int off = 1; off < 64; off <<= 1) {
        #pragma unroll
        for (int u = 0; u < UU; ++u) hacc[u] += __shfl_xor(hacc[u], off, 64);
    }
    float hb[UU];
    #pragma unroll
    for (int u = 0; u < UU; ++u) hb[u] = hacc[u] + b_h[u] + b_eo[u];

    float wsv[UU];
    #pragma unroll
    for (int u = 0; u < UU; ++u) wsv[u] = W_s[u];   // uniform -> s_loads
    const float bs = b_s[0];

    // ---- per-lane W_eo slice (80 VGPRs, reused for all t)
    float wv[8][UU];
    #pragma unroll
    for (int k = 0; k < 2; ++k) {
        #pragma unroll
        for (int j = 0; j < 4; ++j) {
            const float* wr = W_eo + (size_t)(k * 256 + 4 * lane + j) * UU;
            #pragma unroll
            for (int u = 0; u < UU; ++u) wv[k * 4 + j][u] = wr[u];
        }
    }

    // ---- online softmax stream over this wave's 32 t's
    float m = -INFINITY, l = 0.f;
    float c[8];
    #pragma unroll
    for (int j = 0; j < 8; ++j) c[j] = 0.f;

    const int t0 = chunk * CHUNK_T + wave * (CHUNK_T / 4);
    for (int i = 0; i < CHUNK_T / 4; ++i) {
        const int t = t0 + i;
        const float* row = Eo + ((size_t)b * TT + t) * DD;
        float4 e0 = *(const float4*)(row + 4 * lane);          // dense 1KB/instr
        float4 e1 = *(const float4*)(row + 256 + 4 * lane);
        float e[8] = {e0.x, e0.y, e0.z, e0.w, e1.x, e1.y, e1.z, e1.w};

        float acc[UU];
        #pragma unroll
        for (int u = 0; u < UU; ++u) acc[u] = 0.f;
        #pragma unroll
        for (int j = 0; j < 8; ++j) {
            #pragma unroll
            for (int u = 0; u < UU; ++u) acc[u] += e[j] * wv[j][u];
        }
        // butterfly all-reduce: every lane ends with the full 10 dot products
        #pragma unroll
        for (int off = 1; off < 64; off <<= 1) {
            #pragma unroll
            for (int u = 0; u < UU; ++u) acc[u] += __shfl_xor(acc[u], off, 64);
        }
        float s = bs;
        #pragma unroll
        for (int u = 0; u < UU; ++u) s += wsv[u] * fast_tanh(acc[u] + hb[u]);

        if (lane == 0) scores[(size_t)b * TT + t] = s;

        float mn = fmaxf(m, s);
        float f  = __expf(m - mn);     // 1.0 on non-update; 0.0 on first iter
        float p  = __expf(s - mn);
        l = l * f + p;
        #pragma unroll
        for (int j = 0; j < 8; ++j) c[j] = c[j] * f + p * e[j];
        m = mn;
    }

    // ---- combine the block's 4 waves in LDS
    __shared__ float sm[4], sl[4];
    __shared__ float sc[4][DD];
    #pragma unroll
    for (int k = 0; k < 2; ++k) {
        #pragma unroll
        for (int j = 0; j < 4; ++j)
            sc[wave][k * 256 + 4 * lane + j] = c[k * 4 + j];
    }
    if (lane == 0) { sm[wave] = m; sl[wave] = l; }
    __syncthreads();

    float mb = fmaxf(fmaxf(sm[0], sm[1]), fmaxf(sm[2], sm[3]));
    float fw[4];
    #pragma unroll
    for (int w = 0; w < 4; ++w) fw[w] = __expf(sm[w] - mb);
    const int pidx = b * S_CHUNKS + chunk;
    if (tid == 0) {
        pm[pidx] = mb;
        pl[pidx] = sl[0] * fw[0] + sl[1] * fw[1] + sl[2] * fw[2] + sl[3] * fw[3];
    }
    #pragma unroll
    for (int d = tid; d < DD; d += 256) {
        float v = sc[0][d] * fw[0] + sc[1][d] * fw[1] + sc[2][d] * fw[2] + sc[3][d] * fw[3];
        pc[(size_t)pidx * DD + d] = v;
    }
}

// Pass 2: combine S_CHUNKS partials per batch -> context; save final m,l.
__global__ __launch_bounds__(256) void attn_combine(
    const float* __restrict__ pm, const float* __restrict__ pl,
    const float* __restrict__ pc, float* __restrict__ ctx_out,
    float* __restrict__ mf, float* __restrict__ lf)
{
    const int b = blockIdx.x;
    const int tid = threadIdx.x;
    float m = -INFINITY;
    #pragma unroll
    for (int s = 0; s < S_CHUNKS; ++s) m = fmaxf(m, pm[b * S_CHUNKS + s]);
    float fw[S_CHUNKS];
    float l = 0.f;
    #pragma unroll
    for (int s = 0; s < S_CHUNKS; ++s) {
        fw[s] = __expf(pm[b * S_CHUNKS + s] - m);
        l += pl[b * S_CHUNKS + s] * fw[s];
    }
    if (tid == 0) { mf[b] = m; lf[b] = l; }
    const float inv = 1.0f / l;
    #pragma unroll
    for (int d = tid; d < DD; d += 256) {
        float v = 0.f;
        #pragma unroll
        for (int s = 0; s < S_CHUNKS; ++s)
            v += pc[((size_t)(b * S_CHUNKS + s)) * DD + d] * fw[s];
        ctx_out[(size_t)b * DD + d] = v * inv;
    }
}

// Pass 3: weight[b,t] = exp(score - m_b) / l_b
__global__ __launch_bounds__(256) void attn_weights(
    const float* __restrict__ scores, const float* __restrict__ mf,
    const float* __restrict__ lf, float* __restrict__ wout)
{
    const int idx = blockIdx.x * 256 + threadIdx.x;   // B*T total
    const int b = idx >> 11;                          // T = 2048
    wout[idx] = __expf(scores[idx] - mf[b]) / lf[b];
}

extern "C" void kernel_launch(void* const* d_in, const int* in_sizes, int n_in,
                              void* d_out, int out_size, void* d_ws, size_t ws_size,
                              hipStream_t stream) {
    const float* Eo   = (const float*)d_in[0];
    const float* H    = (const float*)d_in[1];
    const float* W_eo = (const float*)d_in[2];
    const float* b_eo = (const float*)d_in[3];
    const float* W_h  = (const float*)d_in[4];
    const float* b_h  = (const float*)d_in[5];
    const float* W_s  = (const float*)d_in[6];
    const float* b_s  = (const float*)d_in[7];

    // workspace layout (floats): scores[B*T] | pm[B*S] | pl[B*S] | mf[B] | lf[B] | pc[B*S*D]
    float* scores = (float*)d_ws;
    float* pm = scores + (size_t)BB * TT;
    float* pl = pm + BB * S_CHUNKS;
    float* mf = pl + BB * S_CHUNKS;
    float* lf = mf + BB;
    float* pc = lf + BB;

    float* out_ctx = (float*)d_out;                 // [B, D]
    float* out_w   = out_ctx + (size_t)BB * DD;     // [B, T, 1]

    dim3 gridA(S_CHUNKS, BB);
    attn_pass1<<<gridA, 256, 0, stream>>>(Eo, H, W_eo, b_eo, W_h, b_h, W_s, b_s,
                                          scores, pm, pl, pc);
    attn_combine<<<BB, 256, 0, stream>>>(pm, pl, pc, out_ctx, mf, lf);
    attn_weights<<<(BB * TT) / 256, 256, 0, stream>>>(scores, mf, lf, out_w);
}

// Round 2
// 77.717 us; speedup vs baseline: 1.6495x; 1.6495x over previous
//
#include <hip/hip_runtime.h>
#include <math.h>

#define BB 64
#define TT 2048
#define DD 512
#define UU 10
#define S_CHUNKS 16
#define CHUNK_T (TT / S_CHUNKS)   // 128 t per block, 32 per wave, 8 batches of 4

__device__ __forceinline__ float fast_tanh(float x) {
    // tanh(x) = 1 - 2/(1+e^{2x}); robust at +-inf
    return 1.0f - 2.0f / (1.0f + __expf(2.0f * x));
}

// Scores are bounded: |s| <= |b_s| + sum|W_s| (tanh in [-1,1]) ~ 4, so exp(s)
// never overflows and softmax needs NO max subtraction: p = exp(s), w = p/sum(p).
__global__ __launch_bounds__(256) void attn_pass1(
    const float* __restrict__ Eo, const float* __restrict__ H,
    const float* __restrict__ W_eo, const float* __restrict__ b_eo,
    const float* __restrict__ W_h, const float* __restrict__ b_h,
    const float* __restrict__ W_s, const float* __restrict__ b_s,
    float* __restrict__ pexp, float* __restrict__ pl, float* __restrict__ pc)
{
    const int b     = blockIdx.y;
    const int chunk = blockIdx.x;
    const int tid   = threadIdx.x;
    const int wave  = tid >> 6;
    const int lane  = tid & 63;

    // ---- hb[u] = (H[b]*W_h)[u] + b_h[u] + b_eo[u]  (once per wave)
    float hacc[UU];
    #pragma unroll
    for (int u = 0; u < UU; ++u) hacc[u] = 0.f;
    const float* Hb = H + (size_t)b * DD;
    #pragma unroll
    for (int k = 0; k < DD / 64; ++k) {
        float hv = Hb[k * 64 + lane];
        const float* wr = W_h + (size_t)(k * 64 + lane) * UU;
        #pragma unroll
        for (int u = 0; u < UU; ++u) hacc[u] += hv * wr[u];
    }
    #pragma unroll
    for (int off = 1; off < 64; off <<= 1) {
        #pragma unroll
        for (int u = 0; u < UU; ++u) hacc[u] += __shfl_xor(hacc[u], off, 64);
    }
    float hb[UU];
    #pragma unroll
    for (int u = 0; u < UU; ++u) hb[u] = hacc[u] + b_h[u] + b_eo[u];

    float wsv[UU];
    #pragma unroll
    for (int u = 0; u < UU; ++u) wsv[u] = W_s[u];   // uniform -> scalar loads
    const float bs = b_s[0];

    // ---- per-lane W_eo slice (80 VGPRs, reused for all t)
    float wv[8][UU];
    #pragma unroll
    for (int k = 0; k < 2; ++k) {
        #pragma unroll
        for (int j = 0; j < 4; ++j) {
            const float* wr = W_eo + (size_t)(k * 256 + 4 * lane + j) * UU;
            #pragma unroll
            for (int u = 0; u < UU; ++u) wv[k * 4 + j][u] = wr[u];
        }
    }

    float l = 0.f;
    float c[8];
    #pragma unroll
    for (int j = 0; j < 8; ++j) c[j] = 0.f;

    const int  t0w  = chunk * CHUNK_T + wave * (CHUNK_T / 4);
    const bool lo32 = (lane & 32) == 0;
    const bool lo16 = (lane & 16) == 0;
    const float* rowbase = Eo + (size_t)b * TT * DD + 4 * lane;

    for (int i = 0; i < CHUNK_T / 16; ++i) {      // 8 batches of 4 t
        const int tb = t0w + i * 4;

        // load e for 4 t's up front (8 independent float4 loads -> MLP)
        float e[4][8];
        #pragma unroll
        for (int tt = 0; tt < 4; ++tt) {
            const float* row = rowbase + (size_t)(tb + tt) * DD;
            float4 e0 = *(const float4*)(row);
            float4 e1 = *(const float4*)(row + 256);
            e[tt][0] = e0.x; e[tt][1] = e0.y; e[tt][2] = e0.z; e[tt][3] = e0.w;
            e[tt][4] = e1.x; e[tt][5] = e1.y; e[tt][6] = e1.z; e[tt][7] = e1.w;
        }

        // per-lane partial projections for 4 t's
        float acc[4][UU];
        #pragma unroll
        for (int tt = 0; tt < 4; ++tt) {
            #pragma unroll
            for (int u = 0; u < UU; ++u) acc[tt][u] = 0.f;
            #pragma unroll
            for (int j = 0; j < 8; ++j) {
                #pragma unroll
                for (int u = 0; u < UU; ++u) acc[tt][u] += e[tt][j] * wv[j][u];
            }
        }

        // fold-reduce: 2 select-folds put t0..t3 into 16-lane groups, then a
        // 4-level butterfly reduces all four t's simultaneously.
        float r[UU];
        #pragma unroll
        for (int u = 0; u < UU; ++u) {
            float y0 = lo32 ? acc[0][u] : acc[2][u];
            float o0 = lo32 ? acc[2][u] : acc[0][u];
            y0 += __shfl_xor(o0, 32, 64);
            float y1 = lo32 ? acc[1][u] : acc[3][u];
            float o1 = lo32 ? acc[3][u] : acc[1][u];
            y1 += __shfl_xor(o1, 32, 64);
            float z  = lo16 ? y0 : y1;
            float oz = lo16 ? y1 : y0;
            z += __shfl_xor(oz, 16, 64);
            z += __shfl_xor(z, 8, 64);
            z += __shfl_xor(z, 4, 64);
            z += __shfl_xor(z, 2, 64);
            z += __shfl_xor(z, 1, 64);
            r[u] = z;   // group g = lane>>4 holds full proj of t = tb + g
        }

        // score -> p for this lane's group-t (tanh amortized: 10 per 4 t)
        float s = bs;
        #pragma unroll
        for (int u = 0; u < UU; ++u) s += wsv[u] * fast_tanh(r[u] + hb[u]);
        float p = __expf(s);

        if ((lane & 15) == 0) pexp[(size_t)b * TT + tb + (lane >> 4)] = p;

        // broadcast the 4 p's; accumulate unnormalized context (no rescale)
        float p0 = __shfl(p, 0, 64);
        float p1 = __shfl(p, 16, 64);
        float p2 = __shfl(p, 32, 64);
        float p3 = __shfl(p, 48, 64);
        l += (p0 + p1) + (p2 + p3);
        #pragma unroll
        for (int j = 0; j < 8; ++j)
            c[j] += p0 * e[0][j] + p1 * e[1][j] + p2 * e[2][j] + p3 * e[3][j];
    }

    // ---- combine the block's 4 waves in LDS
    __shared__ float sl[4];
    __shared__ float sc[4][DD];
    #pragma unroll
    for (int k = 0; k < 2; ++k) {
        #pragma unroll
        for (int j = 0; j < 4; ++j)
            sc[wave][k * 256 + 4 * lane + j] = c[k * 4 + j];
    }
    if (lane == 0) sl[wave] = l;
    __syncthreads();

    const int pidx = b * S_CHUNKS + chunk;
    if (tid == 0) pl[pidx] = (sl[0] + sl[1]) + (sl[2] + sl[3]);
    for (int d = tid; d < DD; d += 256) {
        pc[(size_t)pidx * DD + d] = (sc[0][d] + sc[1][d]) + (sc[2][d] + sc[3][d]);
    }
}

// Pass 2: l = sum of partial l's; context = sum of partial c's / l.
__global__ __launch_bounds__(256) void attn_combine(
    const float* __restrict__ pl, const float* __restrict__ pc,
    float* __restrict__ ctx_out, float* __restrict__ lf)
{
    const int b = blockIdx.x;
    const int tid = threadIdx.x;
    float l = 0.f;
    #pragma unroll
    for (int s = 0; s < S_CHUNKS; ++s) l += pl[b * S_CHUNKS + s];
    if (tid == 0) lf[b] = l;
    const float inv = 1.0f / l;
    for (int d = tid; d < DD; d += 256) {
        float v = 0.f;
        #pragma unroll
        for (int s = 0; s < S_CHUNKS; ++s)
            v += pc[((size_t)(b * S_CHUNKS + s)) * DD + d];
        ctx_out[(size_t)b * DD + d] = v * inv;
    }
}

// Pass 3: weight[b,t] = p[b,t] / l_b
__global__ __launch_bounds__(256) void attn_weights(
    const float* __restrict__ pexp, const float* __restrict__ lf,
    float* __restrict__ wout)
{
    const int idx = blockIdx.x * 256 + threadIdx.x;   // B*T total
    const int b = idx >> 11;                          // T = 2048
    wout[idx] = pexp[idx] / lf[b];
}

extern "C" void kernel_launch(void* const* d_in, const int* in_sizes, int n_in,
                              void* d_out, int out_size, void* d_ws, size_t ws_size,
                              hipStream_t stream) {
    const float* Eo   = (const float*)d_in[0];
    const float* H    = (const float*)d_in[1];
    const float* W_eo = (const float*)d_in[2];
    const float* b_eo = (const float*)d_in[3];
    const float* W_h  = (const float*)d_in[4];
    const float* b_h  = (const float*)d_in[5];
    const float* W_s  = (const float*)d_in[6];
    const float* b_s  = (const float*)d_in[7];

    // ws layout (floats): pexp[B*T] | pl[B*S] | lf[B] | pc[B*S*D]
    float* pexp = (float*)d_ws;
    float* pl = pexp + (size_t)BB * TT;
    float* lf = pl + BB * S_CHUNKS;
    float* pc = lf + BB;

    float* out_ctx = (float*)d_out;                 // [B, D]
    float* out_w   = out_ctx + (size_t)BB * DD;     // [B, T, 1]

    dim3 gridA(S_CHUNKS, BB);
    attn_pass1<<<gridA, 256, 0, stream>>>(Eo, H, W_eo, b_eo, W_h, b_h, W_s, b_s,
                                          pexp, pl, pc);
    attn_combine<<<BB, 256, 0, stream>>>(pl, pc, out_ctx, lf);
    attn_weights<<<(BB * TT) / 256, 256, 0, stream>>>(pexp, lf, out_w);
}